// Round 11
// baseline (1293.096 us; speedup 1.0000x reference)
//
#include <hip/hip_runtime.h>
#include <hip/hip_bf16.h>

typedef unsigned short u16;
typedef unsigned int   u32;
typedef float  f32x4  __attribute__((ext_vector_type(4)));
typedef __bf16 bf16x8 __attribute__((ext_vector_type(8)));
typedef unsigned short u16x4 __attribute__((ext_vector_type(4)));

#define AS1(p) ((const __attribute__((address_space(1))) unsigned int*)(p))
#define AS3(p) ((__attribute__((address_space(3))) unsigned int*)(p))

__device__ __forceinline__ u16 rne_bf16(float f) {
  u32 u = __builtin_bit_cast(u32, f);
  return (u16)((u + 0x7fffu + ((u >> 16) & 1u)) >> 16);
}

// ctl[0] = cvt chunk queue head; ctl[1+slot] = chunks-done per group-slot
__device__ u32 g_ctl[16];

__global__ void zero_ctl() { if (threadIdx.x < 16) g_ctl[threadIdx.x] = 0; }

// ---------------------------------------------------------------------------
// Fused cvt+GEMM table. cvt: 2384 chunks of 32768 elems, buffers ordered by
// GEMM group order (descending NT) so the chunk queue feeds groups in the
// order GEMM blocks need them. GEMM part identical to r9.
// ---------------------------------------------------------------------------
struct FusedTab {
  const float* csrc[16];
  u16*         cdst[16];
  int cstart[16];    // first chunk id of buffer i
  int cslot[16];     // group-slot of buffer i
  int nchunk;
  int target[8];     // chunks per slot
  int slot_of[8];    // group g -> slot
  const u16* A[8];
  const u16* B[8];
  float*     C[8];
  int N[8], K[8];
  int tstart[8];
  int tcnt[8];
  int ngroups;
};

#define BARRIER() do { asm volatile("" ::: "memory");       \
                       __builtin_amdgcn_s_barrier();        \
                       asm volatile("" ::: "memory"); } while (0)

__global__ __launch_bounds__(512) void gemm256_fused(FusedTab t) {
  const int tid  = threadIdx.x;
  __shared__ int shi;

  // ---- tile decode: EXACT r9 (per-group bijective XCD swizzle) ----
  int orig = blockIdx.x;
  int g = 0;
#pragma unroll
  for (int i = 1; i < 8; ++i)
    if (i < t.ngroups && orig >= t.tstart[i]) g = i;
  const int K = t.K[g];
  const int N = t.N[g];
  int local = orig - t.tstart[g];
  int Tg = t.tcnt[g];
  int wl;
  if (Tg & 7) wl = local;
  else        wl = (local & 7) * (Tg >> 3) + (local >> 3);
  int ntn = N >> 8;
  int bm = wl / ntn;
  int bn = wl - bm * ntn;

  // ---- wait/help until this tile's group is fully converted ----
  const int slot = t.slot_of[g];
  bool waited = false;
  while (true) {
    if (tid == 0)
      shi = (int)__hip_atomic_load(&g_ctl[1 + slot], __ATOMIC_RELAXED, __HIP_MEMORY_SCOPE_AGENT);
    __syncthreads();
    int d = shi;
    __syncthreads();
    if (d >= t.target[slot]) break;
    waited = true;
    if (tid == 0) shi = (int)atomicAdd(&g_ctl[0], 1u);
    __syncthreads();
    int c = shi;
    __syncthreads();
    if (c < t.nchunk) {
      int b = 0;
#pragma unroll
      for (int i = 1; i < 16; ++i)
        if (c >= t.cstart[i]) b = i;
      long base4 = ((long)(c - t.cstart[b]) * 32768) >> 2;
      const f32x4* sp = (const f32x4*)t.csrc[b];
      u16x4*       dp = (u16x4*)t.cdst[b];
#pragma unroll
      for (int it = 0; it < 16; ++it) {
        f32x4 v = sp[base4 + it * 512 + tid];
        u16x4 o;
#pragma unroll
        for (int jq = 0; jq < 4; ++jq) o[jq] = rne_bf16(v[jq]);
        dp[base4 + it * 512 + tid] = o;
      }
      asm volatile("s_waitcnt vmcnt(0)" ::: "memory");
      __threadfence();            // L2 writeback: data visible to other XCDs
      __syncthreads();
      if (tid == 0) atomicAdd(&g_ctl[1 + t.cslot[b]], 1u);
      __syncthreads();
    } else {
      __builtin_amdgcn_s_sleep(4);  // all chunks claimed; some still in flight
    }
  }
  if (waited) { __threadfence(); __syncthreads(); }  // acquire: invalidate stale lines

  // ---- GEMM: EXACT r9/r7-validated 8-phase 256x256 inner loop ----
  __shared__ u16 lsA[2 * 16384];   // [buf][256][64]
  __shared__ u16 lsB[2 * 16384];

  const int wid  = tid >> 6;
  const int lane = tid & 63;
  const int wr = wid >> 2;         // 0..1
  const int wc = wid & 3;          // 0..3
  const int l15 = lane & 15;
  const int rl0  = tid >> 3;                                   // 0..63
  const int scol = ((tid & 7) * 8) ^ (((tid >> 3) & 7) << 3);  // swizzled col

  const u16* SA = t.A[g] + (size_t)(bm * 256 + rl0) * K + scol;
  const u16* SB = t.B[g] + (size_t)(bn * 256 + rl0) * K + scol;

  auto stageA = [&](int buf, int half, int kt) {
    const u16* gs = SA + (size_t)half * 128 * K + (size_t)kt * 64;
    u16* ld = &lsA[buf * 16384 + half * 8192 + wid * 512];
#pragma unroll
    for (int c = 0; c < 2; ++c)
      __builtin_amdgcn_global_load_lds(AS1(gs + (size_t)c * 64 * K), AS3(ld + c * 4096), 16, 0, 0);
  };
  auto stageB = [&](int buf, int half, int kt) {
    const u16* gs = SB + (size_t)half * 128 * K + (size_t)kt * 64;
    u16* ld = &lsB[buf * 16384 + half * 8192 + wid * 512];
#pragma unroll
    for (int c = 0; c < 2; ++c)
      __builtin_amdgcn_global_load_lds(AS1(gs + (size_t)c * 64 * K), AS3(ld + c * 4096), 16, 0, 0);
  };

  f32x4 acc[8][4];
#pragma unroll
  for (int i = 0; i < 8; ++i)
#pragma unroll
    for (int j = 0; j < 4; ++j)
      acc[i][j] = (f32x4){0.f, 0.f, 0.f, 0.f};

  bf16x8 a[4][2], b[4][2];
  int acol[2];
#pragma unroll
  for (int s = 0; s < 2; ++s)
    acol[s] = (s * 32 + (lane >> 4) * 8) ^ ((lane & 7) << 3);  // T2 read swizzle

  auto readA = [&](int buf, int mh) {
    const u16* base = &lsA[buf * 16384 + (wr * 128 + mh * 64) * 64];
#pragma unroll
    for (int ii = 0; ii < 4; ++ii)
#pragma unroll
      for (int s = 0; s < 2; ++s)
        a[ii][s] = *(const bf16x8*)&base[(ii * 16 + l15) * 64 + acol[s]];
  };
  auto readB = [&](int buf, int nh) {
    const u16* base = &lsB[buf * 16384 + (wc * 64 + nh * 32) * 64];
#pragma unroll
    for (int jj = 0; jj < 2; ++jj)
#pragma unroll
      for (int s = 0; s < 2; ++s)
        b[nh * 2 + jj][s] = *(const bf16x8*)&base[(jj * 16 + l15) * 64 + acol[s]];
  };
  auto MF = [&](int mh, int nh) {
    __builtin_amdgcn_s_setprio(1);      // T5
#pragma unroll
    for (int ii = 0; ii < 4; ++ii)
#pragma unroll
      for (int jj = 0; jj < 2; ++jj)
#pragma unroll
        for (int s = 0; s < 2; ++s)
          acc[mh * 4 + ii][nh * 2 + jj] =
            __builtin_amdgcn_mfma_f32_16x16x32_bf16(a[ii][s], b[nh * 2 + jj][s],
                                                    acc[mh * 4 + ii][nh * 2 + jj], 0, 0, 0);
    __builtin_amdgcn_s_setprio(0);
  };

  const int NT = K >> 6;
  {
    int k1 = (NT > 1) ? 1 : 0;
    stageA(0, 0, 0); stageA(0, 1, 0); stageB(0, 0, 0); stageB(0, 1, 0);
    stageB(1, 0, k1); stageB(1, 1, k1);
    asm volatile("s_waitcnt vmcnt(4)" ::: "memory");
    BARRIER();
  }

  const int NITER = NT >> 1;
  for (int j = 0; j < NITER; ++j) {
    const int T  = 2 * j;
    const int t1 = (T + 1 < NT) ? T + 1 : NT - 1;
    const int t2 = (T + 2 < NT) ? T + 2 : NT - 1;
    const int t3 = (T + 3 < NT) ? T + 3 : NT - 1;
    // p1
    readA(0, 0); readB(0, 0);
    stageA(1, 0, t1);
    BARRIER();
    MF(0, 0);
    BARRIER();
    // p2
    readB(0, 1);
    stageA(1, 1, t1);
    BARRIER();
    MF(0, 1);
    BARRIER();
    // p3
    readA(0, 1);
    stageB(0, 0, t2);
    BARRIER();
    MF(1, 0);
    BARRIER();
    // p4
    stageB(0, 1, t2);
    BARRIER();
    MF(1, 1);
    asm volatile("s_waitcnt vmcnt(4)" ::: "memory");
    BARRIER();
    // p5
    readA(1, 0); readB(1, 0);
    stageA(0, 0, t2);
    BARRIER();
    MF(0, 0);
    BARRIER();
    // p6
    readB(1, 1);
    stageA(0, 1, t2);
    BARRIER();
    MF(0, 1);
    BARRIER();
    // p7
    readA(1, 1);
    stageB(1, 0, t3);
    BARRIER();
    MF(1, 0);
    BARRIER();
    // p8
    stageB(1, 1, t3);
    BARRIER();
    MF(1, 1);
    asm volatile("s_waitcnt vmcnt(4)" ::: "memory");
    BARRIER();
  }

  // ---- C store, plain cached (C/D layout m89/m91) ----
  float* Cp = t.C[g];
  const int crow = bm * 256 + wr * 128 + (lane >> 4) * 4;
  const int ccol = bn * 256 + wc * 64 + l15;
#pragma unroll
  for (int i = 0; i < 8; ++i)
#pragma unroll
    for (int j = 0; j < 4; ++j)
#pragma unroll
      for (int rr = 0; rr < 4; ++rr)
        Cp[(size_t)(crow + i * 16 + rr) * N + ccol + j * 16] = acc[i][j][rr];
}

// ---------------------------------------------------------------------------
// naive fp32 fallback (only if ws unusable)
// ---------------------------------------------------------------------------
__global__ __launch_bounds__(256) void naive_gemm_f32(const float* __restrict__ X,
                                                      const float* __restrict__ W,
                                                      float* __restrict__ C,
                                                      long MN, int N, int K) {
  long i = (long)blockIdx.x * 256 + threadIdx.x;
  if (i >= MN) return;
  int m = (int)(i / N), n = (int)(i - (long)m * N);
  const float* x = X + (size_t)m * K;
  const float* w = W + (size_t)n * K;
  float s = 0.f;
  for (int k = 0; k < K; ++k) s += x[k] * w[k];
  C[i] = s;
}

// ---------------------------------------------------------------------------
extern "C" void kernel_launch(void* const* d_in, const int* in_sizes, int n_in,
                              void* d_out, int out_size, void* d_ws, size_t ws_size,
                              hipStream_t stream) {
  static const int Ms[8] = {4096, 8192, 2048, 16384, 1024, 4096, 2048, 8192};
  static const int Ks[8] = {1024, 2048,  512,  1024, 2048,  768, 3072, 1024};
  static const int Ns[8] = {2048, 1024, 2048,  1024, 2048, 3072,  768, 4096};
  static const int xs_sz[8] = {4194304, 16777216, 1048576, 16777216, 2097152, 3145728, 6291456, 8388608};
  static const int ws_sz[8] = {2097152,  2097152, 1048576,  1048576, 4194304, 2359296, 2359296, 4194304};
  static const int gorder[8] = {6, 1, 4, 0, 3, 7, 5, 2};   // descending NT

  int ord = 0;
  if (n_in == 16) {
    bool m0 = true, m1 = true, m2 = true, m3 = true;
    for (int i = 0; i < 8; ++i) {
      if (in_sizes[2 * i] != xs_sz[i] || in_sizes[2 * i + 1] != ws_sz[i]) m0 = false;
      if (in_sizes[i] != xs_sz[i]     || in_sizes[8 + i]    != ws_sz[i]) m1 = false;
      if (in_sizes[i] != ws_sz[i]     || in_sizes[8 + i]    != xs_sz[i]) m2 = false;
      if (in_sizes[2 * i] != ws_sz[i] || in_sizes[2 * i + 1] != xs_sz[i]) m3 = false;
    }
    ord = m0 ? 0 : (m1 ? 1 : (m2 ? 2 : (m3 ? 3 : 0)));
  }
  const float* Xs[8];
  const float* Ws[8];
  for (int i = 0; i < 8; ++i) {
    switch (ord) {
      case 0: Xs[i] = (const float*)d_in[2 * i];     Ws[i] = (const float*)d_in[2 * i + 1]; break;
      case 1: Xs[i] = (const float*)d_in[i];         Ws[i] = (const float*)d_in[8 + i];     break;
      case 2: Xs[i] = (const float*)d_in[8 + i];     Ws[i] = (const float*)d_in[i];         break;
      default:Xs[i] = (const float*)d_in[2 * i + 1]; Ws[i] = (const float*)d_in[2 * i];     break;
    }
  }

  size_t xsz[8], wsz[8], osz[8], oofs[8];
  size_t xtot = 0, wtot = 0, ocum = 0;
  for (int i = 0; i < 8; ++i) {
    xsz[i] = (size_t)Ms[i] * Ks[i];
    wsz[i] = (size_t)Ns[i] * Ks[i];
    osz[i] = (size_t)Ms[i] * Ns[i];
    oofs[i] = ocum; ocum += osz[i];
    xtot += xsz[i]; wtot += wsz[i];
  }
  float* out = (float*)d_out;
  size_t need_all = (xtot + wtot) * 2;   // bytes

  auto ovl = [](const void* a, size_t an, const void* b, size_t bn) {
    const char* pa = (const char*)a; const char* pb = (const char*)b;
    return pa < pb + bn && pb < pa + an;
  };
  bool bad_ws = (ws_size < need_all) ||
                ovl(d_ws, need_all, d_out, (size_t)out_size * 4);
  for (int i = 0; i < n_in && !bad_ws; ++i)
    bad_ws = ovl(d_ws, need_all, d_in[i], (size_t)in_sizes[i] * 4);

  if (bad_ws) {
    for (int g = 0; g < 8; ++g) {
      long MN = (long)Ms[g] * Ns[g];
      hipLaunchKernelGGL(naive_gemm_f32, dim3((int)((MN + 255) / 256)), dim3(256), 0, stream,
                         Xs[g], Ws[g], out + oofs[g], MN, Ns[g], Ks[g]);
    }
    return;
  }

  u16* ws = (u16*)d_ws;
  u16* xdst[8]; u16* wdst[8];
  size_t off = 0;
  for (int i = 0; i < 8; ++i) { xdst[i] = ws + off; off += xsz[i]; }
  for (int i = 0; i < 8; ++i) { wdst[i] = ws + off; off += wsz[i]; }

  FusedTab t{};
  // cvt chunk layout: group-ordered (x then w per group), 32768 elems/chunk
  int cb = 0;
  for (int s = 0; s < 8; ++s) {
    int g = gorder[s];
    t.slot_of[g] = s;
    t.csrc[2 * s]     = Xs[g]; t.cdst[2 * s]     = xdst[g];
    t.cstart[2 * s]   = cb;    t.cslot[2 * s]    = s;
    cb += (int)(xsz[g] / 32768);
    t.csrc[2 * s + 1] = Ws[g]; t.cdst[2 * s + 1] = wdst[g];
    t.cstart[2 * s + 1] = cb;  t.cslot[2 * s + 1] = s;
    cb += (int)(wsz[g] / 32768);
    t.target[s] = (int)((xsz[g] + wsz[g]) / 32768);
  }
  t.nchunk = cb;
  // gemm tables: dispatch order = group order (descending NT), r9 layout
  int tiles = 0;
  for (int s = 0; s < 8; ++s) {
    int g = gorder[s];
    t.A[s] = xdst[g]; t.B[s] = wdst[g]; t.C[s] = out + oofs[g];
    t.N[s] = Ns[g]; t.K[s] = Ks[g];
    t.tstart[s] = tiles;
    t.tcnt[s] = (Ms[g] >> 8) * (Ns[g] >> 8);
    tiles += t.tcnt[s];
  }
  // slot_of must map the GEMM table's group index (= slot) to cvt slot: identity
  for (int s = 0; s < 8; ++s) t.slot_of[s] = s;
  t.ngroups = 8;

  hipLaunchKernelGGL(zero_ctl, dim3(1), dim3(64), 0, stream);
  hipLaunchKernelGGL(gemm256_fused, dim3(tiles), dim3(512), 0, stream, t);
}

// Round 12
// 348.456 us; speedup vs baseline: 3.7109x; 3.7109x over previous
//
#include <hip/hip_runtime.h>
#include <hip/hip_bf16.h>

typedef unsigned short u16;
typedef unsigned int   u32;
typedef float  f32x4  __attribute__((ext_vector_type(4)));
typedef __bf16 bf16x8 __attribute__((ext_vector_type(8)));
typedef unsigned short u16x4 __attribute__((ext_vector_type(4)));

#define AS1(p) ((const __attribute__((address_space(1))) unsigned int*)(p))
#define AS3(p) ((__attribute__((address_space(3))) unsigned int*)(p))

__device__ __forceinline__ u16 rne_bf16(float f) {
  u32 u = __builtin_bit_cast(u32, f);
  return (u16)((u + 0x7fffu + ((u >> 16) & 1u)) >> 16);
}

// ---------------------------------------------------------------------------
// fp32 -> bf16, one-shot table-driven (r7 config — best measured total)
// ---------------------------------------------------------------------------
struct CvtTable {
  const float* src[16];
  u16*         dst[16];
  int blk_start[16];
  int nbuf;
};

__global__ __launch_bounds__(256) void cvt_f32_to_bf16(CvtTable t) {
  int blk = blockIdx.x;
  int b = 0;
#pragma unroll
  for (int i = 1; i < 16; ++i)
    if (i < t.nbuf && blk >= t.blk_start[i]) b = i;
  long off4 = (long)(blk - t.blk_start[b]) * 256 + threadIdx.x;
  f32x4 v = ((const f32x4*)t.src[b])[off4];
  u16x4 o;
#pragma unroll
  for (int j = 0; j < 4; ++j) o[j] = rne_bf16(v[j]);
  ((u16x4*)t.dst[b])[off4] = o;
}

// ---------------------------------------------------------------------------
// Grouped bf16 GEMM, 8-phase 256x256 — EXACT r7 configuration (736 TF,
// best measured): per-group bijective XCD swizzle, T2 pre-swizzled staging +
// swizzled ds_read, counted vmcnt(4) at p4/p8 (T4), setprio (T5), plain
// cached C stores. Dispatch-style grid (r10 persistent & r11 fused both
// regressed — CP dynamic placement beats static schedules here).
// ---------------------------------------------------------------------------
struct GemmTable {
  const u16* A[8];
  const u16* B[8];
  float*     C[8];
  int N[8], K[8];
  int tstart[8];
  int tcnt[8];
  int ngroups;
  int total;
};

#define BARRIER() do { asm volatile("" ::: "memory");       \
                       __builtin_amdgcn_s_barrier();        \
                       asm volatile("" ::: "memory"); } while (0)

__global__ __launch_bounds__(512) void gemm256_8ph(GemmTable t) {
  int orig = blockIdx.x;
  int g = 0;
#pragma unroll
  for (int i = 1; i < 8; ++i)
    if (i < t.ngroups && orig >= t.tstart[i]) g = i;

  const int K = t.K[g];
  const int N = t.N[g];

  int local = orig - t.tstart[g];
  int Tg = t.tcnt[g];
  int wl;
  if (Tg & 7) wl = local;
  else        wl = (local & 7) * (Tg >> 3) + (local >> 3);
  int ntn = N >> 8;
  int bm = wl / ntn;
  int bn = wl - bm * ntn;

  __shared__ u16 lsA[2 * 16384];   // [buf][256][64]
  __shared__ u16 lsB[2 * 16384];

  const int tid  = threadIdx.x;
  const int wid  = tid >> 6;
  const int lane = tid & 63;
  const int wr = wid >> 2;         // 0..1
  const int wc = wid & 3;          // 0..3
  const int l15 = lane & 15;

  const int rl0  = tid >> 3;                                   // 0..63
  const int scol = ((tid & 7) * 8) ^ (((tid >> 3) & 7) << 3);  // swizzled col
  const u16* SA = t.A[g] + (size_t)(bm * 256 + rl0) * K + scol;
  const u16* SB = t.B[g] + (size_t)(bn * 256 + rl0) * K + scol;

  auto stageA = [&](int buf, int half, int kt) {
    const u16* gs = SA + (size_t)half * 128 * K + (size_t)kt * 64;
    u16* ld = &lsA[buf * 16384 + half * 8192 + wid * 512];
#pragma unroll
    for (int c = 0; c < 2; ++c)
      __builtin_amdgcn_global_load_lds(AS1(gs + (size_t)c * 64 * K), AS3(ld + c * 4096), 16, 0, 0);
  };
  auto stageB = [&](int buf, int half, int kt) {
    const u16* gs = SB + (size_t)half * 128 * K + (size_t)kt * 64;
    u16* ld = &lsB[buf * 16384 + half * 8192 + wid * 512];
#pragma unroll
    for (int c = 0; c < 2; ++c)
      __builtin_amdgcn_global_load_lds(AS1(gs + (size_t)c * 64 * K), AS3(ld + c * 4096), 16, 0, 0);
  };

  f32x4 acc[8][4];
#pragma unroll
  for (int i = 0; i < 8; ++i)
#pragma unroll
    for (int j = 0; j < 4; ++j)
      acc[i][j] = (f32x4){0.f, 0.f, 0.f, 0.f};

  bf16x8 a[4][2], b[4][2];
  int acol[2];
#pragma unroll
  for (int s = 0; s < 2; ++s)
    acol[s] = (s * 32 + (lane >> 4) * 8) ^ ((lane & 7) << 3);  // T2 read swizzle

  auto readA = [&](int buf, int mh) {
    const u16* base = &lsA[buf * 16384 + (wr * 128 + mh * 64) * 64];
#pragma unroll
    for (int ii = 0; ii < 4; ++ii)
#pragma unroll
      for (int s = 0; s < 2; ++s)
        a[ii][s] = *(const bf16x8*)&base[(ii * 16 + l15) * 64 + acol[s]];
  };
  auto readB = [&](int buf, int nh) {
    const u16* base = &lsB[buf * 16384 + (wc * 64 + nh * 32) * 64];
#pragma unroll
    for (int jj = 0; jj < 2; ++jj)
#pragma unroll
      for (int s = 0; s < 2; ++s)
        b[nh * 2 + jj][s] = *(const bf16x8*)&base[(jj * 16 + l15) * 64 + acol[s]];
  };
  auto MF = [&](int mh, int nh) {
    __builtin_amdgcn_s_setprio(1);      // T5
#pragma unroll
    for (int ii = 0; ii < 4; ++ii)
#pragma unroll
      for (int jj = 0; jj < 2; ++jj)
#pragma unroll
        for (int s = 0; s < 2; ++s)
          acc[mh * 4 + ii][nh * 2 + jj] =
            __builtin_amdgcn_mfma_f32_16x16x32_bf16(a[ii][s], b[nh * 2 + jj][s],
                                                    acc[mh * 4 + ii][nh * 2 + jj], 0, 0, 0);
    __builtin_amdgcn_s_setprio(0);
  };

  // ---- prologue: tile0 (A+B) + tile1 B halves in flight ----
  const int NT = K >> 6;
  {
    int k1 = (NT > 1) ? 1 : 0;
    stageA(0, 0, 0); stageA(0, 1, 0); stageB(0, 0, 0); stageB(0, 1, 0);
    stageB(1, 0, k1); stageB(1, 1, k1);
    asm volatile("s_waitcnt vmcnt(4)" ::: "memory");
    BARRIER();
  }

  const int NITER = NT >> 1;
  for (int j = 0; j < NITER; ++j) {
    const int T  = 2 * j;
    const int t1 = (T + 1 < NT) ? T + 1 : NT - 1;
    const int t2 = (T + 2 < NT) ? T + 2 : NT - 1;
    const int t3 = (T + 3 < NT) ? T + 3 : NT - 1;
    // p1
    readA(0, 0); readB(0, 0);
    stageA(1, 0, t1);
    BARRIER();
    MF(0, 0);
    BARRIER();
    // p2
    readB(0, 1);
    stageA(1, 1, t1);
    BARRIER();
    MF(0, 1);
    BARRIER();
    // p3
    readA(0, 1);
    stageB(0, 0, t2);
    BARRIER();
    MF(1, 0);
    BARRIER();
    // p4
    stageB(0, 1, t2);
    BARRIER();
    MF(1, 1);
    asm volatile("s_waitcnt vmcnt(4)" ::: "memory");
    BARRIER();
    // p5
    readA(1, 0); readB(1, 0);
    stageA(0, 0, t2);
    BARRIER();
    MF(0, 0);
    BARRIER();
    // p6
    readB(1, 1);
    stageA(0, 1, t2);
    BARRIER();
    MF(0, 1);
    BARRIER();
    // p7
    readA(1, 1);
    stageB(1, 0, t3);
    BARRIER();
    MF(1, 0);
    BARRIER();
    // p8
    stageB(1, 1, t3);
    BARRIER();
    MF(1, 1);
    asm volatile("s_waitcnt vmcnt(4)" ::: "memory");
    BARRIER();
  }

  // ---- C store, plain cached stores (C/D layout m89/m91) ----
  float* Cp = t.C[g];
  const int crow = bm * 256 + wr * 128 + (lane >> 4) * 4;
  const int ccol = bn * 256 + wc * 64 + l15;
#pragma unroll
  for (int i = 0; i < 8; ++i)
#pragma unroll
    for (int j = 0; j < 4; ++j)
#pragma unroll
      for (int rr = 0; rr < 4; ++rr)
        Cp[(size_t)(crow + i * 16 + rr) * N + ccol + j * 16] = acc[i][j][rr];
}

// ---------------------------------------------------------------------------
// naive fp32 fallback (only if ws unusable)
// ---------------------------------------------------------------------------
__global__ __launch_bounds__(256) void naive_gemm_f32(const float* __restrict__ X,
                                                      const float* __restrict__ W,
                                                      float* __restrict__ C,
                                                      long MN, int N, int K) {
  long i = (long)blockIdx.x * 256 + threadIdx.x;
  if (i >= MN) return;
  int m = (int)(i / N), n = (int)(i - (long)m * N);
  const float* x = X + (size_t)m * K;
  const float* w = W + (size_t)n * K;
  float s = 0.f;
  for (int k = 0; k < K; ++k) s += x[k] * w[k];
  C[i] = s;
}

// ---------------------------------------------------------------------------
extern "C" void kernel_launch(void* const* d_in, const int* in_sizes, int n_in,
                              void* d_out, int out_size, void* d_ws, size_t ws_size,
                              hipStream_t stream) {
  static const int Ms[8] = {4096, 8192, 2048, 16384, 1024, 4096, 2048, 8192};
  static const int Ks[8] = {1024, 2048,  512,  1024, 2048,  768, 3072, 1024};
  static const int Ns[8] = {2048, 1024, 2048,  1024, 2048, 3072,  768, 4096};
  static const int xs_sz[8] = {4194304, 16777216, 1048576, 16777216, 2097152, 3145728, 6291456, 8388608};
  static const int ws_sz[8] = {2097152,  2097152, 1048576,  1048576, 4194304, 2359296, 2359296, 4194304};
  static const int gorder[8] = {6, 1, 4, 0, 3, 7, 5, 2};   // descending K

  int ord = 0;
  if (n_in == 16) {
    bool m0 = true, m1 = true, m2 = true, m3 = true;
    for (int i = 0; i < 8; ++i) {
      if (in_sizes[2 * i] != xs_sz[i] || in_sizes[2 * i + 1] != ws_sz[i]) m0 = false;
      if (in_sizes[i] != xs_sz[i]     || in_sizes[8 + i]    != ws_sz[i]) m1 = false;
      if (in_sizes[i] != ws_sz[i]     || in_sizes[8 + i]    != xs_sz[i]) m2 = false;
      if (in_sizes[2 * i] != ws_sz[i] || in_sizes[2 * i + 1] != xs_sz[i]) m3 = false;
    }
    ord = m0 ? 0 : (m1 ? 1 : (m2 ? 2 : (m3 ? 3 : 0)));
  }
  const float* Xs[8];
  const float* Ws[8];
  for (int i = 0; i < 8; ++i) {
    switch (ord) {
      case 0: Xs[i] = (const float*)d_in[2 * i];     Ws[i] = (const float*)d_in[2 * i + 1]; break;
      case 1: Xs[i] = (const float*)d_in[i];         Ws[i] = (const float*)d_in[8 + i];     break;
      case 2: Xs[i] = (const float*)d_in[8 + i];     Ws[i] = (const float*)d_in[i];         break;
      default:Xs[i] = (const float*)d_in[2 * i + 1]; Ws[i] = (const float*)d_in[2 * i];     break;
    }
  }

  size_t xsz[8], wsz[8], osz[8], oofs[8];
  size_t xtot = 0, wtot = 0, ocum = 0;
  for (int i = 0; i < 8; ++i) {
    xsz[i] = (size_t)Ms[i] * Ks[i];
    wsz[i] = (size_t)Ns[i] * Ks[i];
    osz[i] = (size_t)Ms[i] * Ns[i];
    oofs[i] = ocum; ocum += osz[i];
    xtot += xsz[i]; wtot += wsz[i];
  }
  float* out = (float*)d_out;
  size_t need_all = (xtot + wtot) * 2;   // bytes

  auto ovl = [](const void* a, size_t an, const void* b, size_t bn) {
    const char* pa = (const char*)a; const char* pb = (const char*)b;
    return pa < pb + bn && pb < pa + an;
  };
  bool bad_ws = (ws_size < need_all) ||
                ovl(d_ws, need_all, d_out, (size_t)out_size * 4);
  for (int i = 0; i < n_in && !bad_ws; ++i)
    bad_ws = ovl(d_ws, need_all, d_in[i], (size_t)in_sizes[i] * 4);

  if (bad_ws) {
    for (int g = 0; g < 8; ++g) {
      long MN = (long)Ms[g] * Ns[g];
      hipLaunchKernelGGL(naive_gemm_f32, dim3((int)((MN + 255) / 256)), dim3(256), 0, stream,
                         Xs[g], Ws[g], out + oofs[g], MN, Ns[g], Ks[g]);
    }
    return;
  }

  u16* ws = (u16*)d_ws;
  u16* xdst[8]; u16* wdst[8];
  size_t off = 0;
  for (int i = 0; i < 8; ++i) { xdst[i] = ws + off; off += xsz[i]; }
  for (int i = 0; i < 8; ++i) { wdst[i] = ws + off; off += wsz[i]; }

  CvtTable ct{};
  int cb = 0;
  for (int i = 0; i < 16; ++i) {
    const float* s = (i < 8) ? Xs[i] : Ws[i - 8];
    u16* d        = (i < 8) ? xdst[i] : wdst[i - 8];
    size_t n      = (i < 8) ? xsz[i] : wsz[i - 8];
    ct.src[i] = s; ct.dst[i] = d; ct.blk_start[i] = cb;
    cb += (int)(n / 1024);
  }
  ct.nbuf = 16;
  hipLaunchKernelGGL(cvt_f32_to_bf16, dim3(cb), dim3(256), 0, stream, ct);

  GemmTable gt{};
  int tiles = 0;
  for (int s = 0; s < 8; ++s) {
    int i = gorder[s];
    gt.A[s] = xdst[i]; gt.B[s] = wdst[i]; gt.C[s] = out + oofs[i];
    gt.N[s] = Ns[i]; gt.K[s] = Ks[i];
    gt.tstart[s] = tiles;
    gt.tcnt[s] = (Ms[i] >> 8) * (Ns[i] >> 8);
    tiles += gt.tcnt[s];
  }
  gt.ngroups = 8; gt.total = tiles;
  hipLaunchKernelGGL(gemm256_8ph, dim3(tiles), dim3(512), 0, stream, gt);
}